// Round 6
// baseline (259.455 us; speedup 1.0000x reference)
//
#include <hip/hip_runtime.h>

typedef __bf16 bf16_t;
typedef __bf16 bf16x8 __attribute__((ext_vector_type(8)));
typedef __bf16 bf16x4 __attribute__((ext_vector_type(4)));
typedef float f32x4 __attribute__((ext_vector_type(4)));
typedef unsigned short ushort_t;

#define T_SEQ 2048
#define C_DIM 1024
#define NH    16
#define HD    64

__device__ __forceinline__ ushort_t f2bf(float f) {
    unsigned u = __builtin_bit_cast(unsigned, f);
    u += 0x7FFFu + ((u >> 16) & 1u);   // RNE
    return (ushort_t)(u >> 16);
}

// async 16B global -> LDS (direct, no VGPR round-trip)
__device__ __forceinline__ void async_cp16(const void* g, void* l) {
    __builtin_amdgcn_global_load_lds(
        (const __attribute__((address_space(1))) void*)g,
        (__attribute__((address_space(3))) void*)l, 16, 0, 0);
}

// ---------------------------------------------------------------------------
// Unified fp32 -> bf16 conversion for x, Wq, Wk, Wv (+ optionally Wp).
// Grid 11264 blocks: x,Wq,Wk,Wv.  Grid 12288: also Wp (when ws is big enough).
// ---------------------------------------------------------------------------
#define X4  2097152
#define W4  262144
__global__ __launch_bounds__(256)
void cvt_all_kernel(const float* __restrict__ x,  const float* __restrict__ Wq,
                    const float* __restrict__ Wk, const float* __restrict__ Wv,
                    const float* __restrict__ Wp,
                    ushort_t* __restrict__ xb,  ushort_t* __restrict__ Wqb,
                    ushort_t* __restrict__ Wkb, ushort_t* __restrict__ Wvb,
                    ushort_t* __restrict__ Wpb) {
    int i = blockIdx.x * 256 + threadIdx.x;
    const float* src; ushort_t* dst; int off;
    if (i < X4)                { src = x;  dst = xb;  off = i; }
    else if (i < X4 + W4)      { src = Wq; dst = Wqb; off = i - X4; }
    else if (i < X4 + 2 * W4)  { src = Wk; dst = Wkb; off = i - X4 - W4; }
    else if (i < X4 + 3 * W4)  { src = Wv; dst = Wvb; off = i - X4 - 2 * W4; }
    else                       { src = Wp; dst = Wpb; off = i - X4 - 3 * W4; }
    float4 f = ((const float4*)src)[off];
    ushort4 u;
    u.x = f2bf(f.x); u.y = f2bf(f.y); u.z = f2bf(f.z); u.w = f2bf(f.w);
    ((ushort4*)dst)[off] = u;
}

// fp32 -> bf16 for Wp (fallback: runs after flash into the dead Qw region)
__global__ __launch_bounds__(256)
void cvt_wp_kernel(const float* __restrict__ Wp, ushort_t* __restrict__ Wpb) {
    int i = blockIdx.x * 256 + threadIdx.x;   // 262144 float4
    float4 f = ((const float4*)Wp)[i];
    ushort4 u;
    u.x = f2bf(f.x); u.y = f2bf(f.y); u.z = f2bf(f.z); u.w = f2bf(f.w);
    ((ushort4*)Wpb)[i] = u;
}

// ---------------------------------------------------------------------------
// GEMM core: 128x128 tile, BK=64, 256 threads (4 waves, 2x2), NT layout,
// all-bf16.  Staging via global_load_lds (16B/lane, linear LDS dest).
// XOR swizzle via pre-swizzled GLOBAL source; fragment reads apply the same
// involution -> conflict-free ds_read_b128.
// SWAP=false: acc[i][j] holds C[m = i*16+quad*4+r][n = j*16+ln]
// SWAP=true : mfma(bfr, af) -> acc[i][j] holds C[m = i*16+ln][n = j*16+quad*4+r]
//             i.e. 4 CONSECUTIVE n per thread -> vectorized stores along n.
// NOTE: each __global__ kernel must instantiate EXACTLY ONE variant —
// instantiating both in one kernel doubles static LDS (R4 regression).
// ---------------------------------------------------------------------------
template<bool SWAP>
__device__ __forceinline__ void gemm_core_128(const bf16_t* __restrict__ A,
                                              const bf16_t* __restrict__ B,
                                              f32x4 (&acc)[4][4]) {
    __shared__ alignas(16) ushort_t As[128 * 64];
    __shared__ alignas(16) ushort_t Ws[128 * 64];
    const int tid  = threadIdx.x;
    const int lane = tid & 63;
    const int wv   = tid >> 6;
    const int wm   = wv >> 1, wn = wv & 1;
    const int quad = lane >> 4, ln = lane & 15;
    const int m0 = blockIdx.x * 128, n0 = blockIdx.y * 128;

    f32x4 z4 = {0.f, 0.f, 0.f, 0.f};
#pragma unroll
    for (int i = 0; i < 4; i++)
#pragma unroll
        for (int j = 0; j < 4; j++) acc[i][j] = z4;

    const int lr = lane >> 3;            // row within 8-row chunk
    const int lc = (lane & 7) ^ lr;      // swizzled source 16B-block
    const bf16_t* Ab = A + (size_t)(m0 + wv * 32 + lr) * 1024 + lc * 8;
    const bf16_t* Bb = B + (size_t)(n0 + wv * 32 + lr) * 1024 + lc * 8;

    for (int kt = 0; kt < 1024; kt += 64) {
#pragma unroll
        for (int p = 0; p < 4; ++p) {
            async_cp16(Ab + (size_t)p * 8192 + kt, &As[(wv * 4 + p) * 512]);
            async_cp16(Bb + (size_t)p * 8192 + kt, &Ws[(wv * 4 + p) * 512]);
        }
        __syncthreads();
#pragma unroll
        for (int ks = 0; ks < 2; ++ks) {
            bf16x8 af[4], bfr[4];
#pragma unroll
            for (int i = 0; i < 4; i++)
                af[i] = *(const bf16x8*)&As[(wm * 64 + i * 16 + ln) * 64 +
                                            (((ks * 4 + quad) ^ (ln & 7)) * 8)];
#pragma unroll
            for (int j = 0; j < 4; j++)
                bfr[j] = *(const bf16x8*)&Ws[(wn * 64 + j * 16 + ln) * 64 +
                                             (((ks * 4 + quad) ^ (ln & 7)) * 8)];
#pragma unroll
            for (int i = 0; i < 4; i++)
#pragma unroll
                for (int j = 0; j < 4; j++)
                    acc[i][j] = SWAP
                        ? __builtin_amdgcn_mfma_f32_16x16x32_bf16(bfr[j], af[i],
                                                                  acc[i][j], 0, 0, 0)
                        : __builtin_amdgcn_mfma_f32_16x16x32_bf16(af[i], bfr[j],
                                                                  acc[i][j], 0, 0, 0);
        }
        __syncthreads();
    }
}

// ---------------------------------------------------------------------------
// Q/K projection (SWAP layout -> ushort4 stores along d).
// z=0: Q (pre-scaled by (1/8)*log2(e)); z=1: K.  Output [B,H,T,D] bf16.
// ---------------------------------------------------------------------------
__global__ __launch_bounds__(256, 3)
void qk_gemm_kernel(const bf16_t* __restrict__ xb,
                    const bf16_t* __restrict__ Wqb, const float* __restrict__ bq,
                    const bf16_t* __restrict__ Wkb, const float* __restrict__ bk,
                    ushort_t* __restrict__ Qo, ushort_t* __restrict__ Ko) {
    const int z = blockIdx.z;
    const bf16_t* W   = z ? Wkb : Wqb;
    const float* bias = z ? bk : bq;
    ushort_t* outp    = z ? Ko : Qo;
    const float fs    = z ? 1.0f : 0.18033688011112042f;  // (1/8)*log2(e)

    f32x4 acc[4][4];
    gemm_core_128<true>(xb, W, acc);

    const int tid  = threadIdx.x;
    const int lane = tid & 63;
    const int wv2  = tid >> 6;
    const int wm   = wv2 >> 1, wn = wv2 & 1;
    const int quad = lane >> 4, ln = lane & 15;
    const int mbase = blockIdx.x * 128 + wm * 64;
    const int nbase = blockIdx.y * 128 + wn * 64;

    // acc[i][j]: m = mbase + i*16 + ln ; n = nbase + j*16 + quad*4 + r
#pragma unroll
    for (int j = 0; j < 4; j++) {
        int nb = nbase + j * 16 + quad * 4;
        float4 b4 = *(const float4*)&bias[nb];
        int h = nb >> 6, d = nb & 63;
#pragma unroll
        for (int i = 0; i < 4; i++) {
            int m = mbase + i * 16 + ln;
            int b = m >> 11, t = m & 2047;
            ushort4 us;
            us.x = f2bf((acc[i][j][0] + b4.x) * fs);
            us.y = f2bf((acc[i][j][1] + b4.y) * fs);
            us.z = f2bf((acc[i][j][2] + b4.z) * fs);
            us.w = f2bf((acc[i][j][3] + b4.w) * fs);
            *(ushort4*)(outp + ((size_t)(b * NH + h) * T_SEQ + t) * HD + d) = us;
        }
    }
}

// ---------------------------------------------------------------------------
// V projection (non-SWAP -> t-contiguous ushort4 stores).  Output [B,H,D,T].
// ---------------------------------------------------------------------------
__global__ __launch_bounds__(256, 3)
void v_gemm_kernel(const bf16_t* __restrict__ xb,
                   const bf16_t* __restrict__ Wvb, const float* __restrict__ bv,
                   ushort_t* __restrict__ Vo) {
    f32x4 acc[4][4];
    gemm_core_128<false>(xb, Wvb, acc);

    const int tid  = threadIdx.x;
    const int lane = tid & 63;
    const int wv2  = tid >> 6;
    const int wm   = wv2 >> 1, wn = wv2 & 1;
    const int quad = lane >> 4, ln = lane & 15;
    const int mbase = blockIdx.x * 128 + wm * 64;
    const int nbase = blockIdx.y * 128 + wn * 64;

    // acc[i][j]: m = mbase + i*16 + quad*4 + r ; n = nbase + j*16 + ln
#pragma unroll
    for (int j = 0; j < 4; j++) {
        int n = nbase + j * 16 + ln;
        float bj = bv[n];
        int h = n >> 6, d = n & 63;
#pragma unroll
        for (int i = 0; i < 4; i++) {
            int mr = mbase + i * 16 + quad * 4;
            int b = mr >> 11, t = mr & 2047;
            ushort4 us;
            us.x = f2bf(acc[i][j][0] + bj);
            us.y = f2bf(acc[i][j][1] + bj);
            us.z = f2bf(acc[i][j][2] + bj);
            us.w = f2bf(acc[i][j][3] + bj);
            *(ushort4*)(Vo + ((size_t)(b * NH + h) * HD + d) * T_SEQ + t) = us;
        }
    }
}

// ---------------------------------------------------------------------------
// Flash attention (causal), paired q-tiles (p, 31-p), P HELD IN REGISTERS,
// K/V LDS DOUBLE-BUFFERED (stride-64 + 16B-block XOR swizzle, 32 KB total ->
// 5 blocks/CU), ONE barrier per iteration, 2-tile-deep global prefetch,
// s_setprio(1) around the MFMA clusters (T5).
//
// Swapped QK: zz = mfma(K,Q) -> lane (quad,ln) holds P[q=ln][s=n16*16+quad*4+r].
// PV uses a PERMUTED k-order matching where those values already sit; V is
// staged into LDS in the same s-permutation (vkpos).  Rowsum-MFMA vs ones is
// permutation-invariant.
// LDS swizzle: 16B-block index ^= (row & 7), applied at BOTH write and read
// (reg-staged stores -> both sides controllable; rule 21 satisfied).
// ---------------------------------------------------------------------------
__device__ __forceinline__ int vkpos(int s) {   // k-slot position of s in [0,64)
    return 32 * (s >> 5) + 8 * ((s >> 2) & 3) + 4 * ((s >> 4) & 1) + (s & 3);
}

__global__ __launch_bounds__(256, 4)
void flash_kernel(const ushort_t* __restrict__ Qw, const ushort_t* __restrict__ Kw,
                  const ushort_t* __restrict__ Vt, ushort_t* __restrict__ Y) {
    __shared__ alignas(16) ushort_t Ks[2][64 * 64];
    __shared__ alignas(16) ushort_t Vts[2][64 * 64];

    const int tid  = threadIdx.x;
    const int lane = tid & 63;
    const int wv   = tid >> 6;
    const int quad = lane >> 4, ln = lane & 15;
    // bijective XCD-aware remap of (p, bh)
    const int L  = blockIdx.y * 16 + blockIdx.x;      // hw dispatch-linear id
    const int m  = L >> 3;
    const int bh = ((m >> 4) << 3) | (L & 7);         // same bh -> same L%8 (XCD)
    const int p  = m & 15;                            // 0..15
    const int qa = p, qb = 31 - p;
    const int b = bh >> 4, h = bh & 15;

    bf16x8 ones;
#pragma unroll
    for (int i = 0; i < 8; i++) ones[i] = (bf16_t)1.0f;

    const ushort_t* qpa = Qw + ((size_t)bh * T_SEQ + qa * 64 + wv * 16 + ln) * HD;
    const ushort_t* qpb = Qw + ((size_t)bh * T_SEQ + qb * 64 + wv * 16 + ln) * HD;
    bf16x8 aqA0 = *(const bf16x8*)(qpa + quad * 8);
    bf16x8 aqA1 = *(const bf16x8*)(qpa + 32 + quad * 8);
    bf16x8 aqB0 = *(const bf16x8*)(qpb + quad * 8);
    bf16x8 aqB1 = *(const bf16x8*)(qpb + 32 + quad * 8);

    f32x4 oA[4], oB[4];
    f32x4 z4 = {0.f, 0.f, 0.f, 0.f};
#pragma unroll
    for (int i = 0; i < 4; i++) { oA[i] = z4; oB[i] = z4; }
    f32x4 lA4 = z4, lB4 = z4;

    const int row0 = tid >> 3, c80 = (tid & 7) * 8;
    const int row1 = row0 + 32;
    // swizzled K dest (16B-block ^= row&7); row1&7 == row0&7
    const int kblk  = ((c80 >> 3) ^ (row0 & 7)) << 3;
    const int kdst0 = row0 * 64 + kblk;
    const int kdst1 = row1 * 64 + kblk;
    // swizzled V dest: permuted k-slot, then block-XOR (8B-aligned within block)
    const int kp0 = vkpos(c80);          // V k-slot for s = c80..c80+3
    const int kp1 = vkpos(c80 + 4);      // V k-slot for s = c80+4..c80+7
    const int vo0 = (((kp0 >> 3) ^ (row0 & 7)) << 3) + (kp0 & 7);
    const int vo1 = (((kp1 >> 3) ^ (row0 & 7)) << 3) + (kp1 & 7);
    const int vdst00 = row0 * 64 + vo0, vdst01 = row0 * 64 + vo1;
    const int vdst10 = row1 * 64 + vo0, vdst11 = row1 * 64 + vo1;

    uint4 pk0, pk1, pv0, pv1;
    auto load_tile = [&](int sb) {
        pk0 = *(const uint4*)(Kw + ((size_t)bh * T_SEQ + sb + row0) * HD + c80);
        pv0 = *(const uint4*)(Vt + ((size_t)bh * HD + row0) * T_SEQ + sb + c80);
        pk1 = *(const uint4*)(Kw + ((size_t)bh * T_SEQ + sb + row1) * HD + c80);
        pv1 = *(const uint4*)(Vt + ((size_t)bh * HD + row1) * T_SEQ + sb + c80);
    };
    auto store_tile = [&](int bs) {
        *(uint4*)&Ks[bs][kdst0] = pk0;
        *(uint4*)&Ks[bs][kdst1] = pk1;
        uint2 a0 = {pv0.x, pv0.y}, a1 = {pv0.z, pv0.w};
        uint2 b0 = {pv1.x, pv1.y}, b1 = {pv1.z, pv1.w};
        *(uint2*)&Vts[bs][vdst00] = a0;
        *(uint2*)&Vts[bs][vdst01] = a1;
        *(uint2*)&Vts[bs][vdst10] = b0;
        *(uint2*)&Vts[bs][vdst11] = b1;
    };

    const int qrow = wv * 16 + ln;       // this lane's q position within tile
    const int rm = ln & 7;               // read-side swizzle key (row & 7)

    // prologue: tile0 -> buf0; regs hold tile1; invariant at loop entry:
    //   buf[st&1] is full with tile st, regs hold tile st+1
    load_tile(0);
    store_tile(0);
    load_tile(64);
    __syncthreads();

    for (int st = 0; st <= qb; ++st) {
        const int cur = st & 1;
        if (st < qb) store_tile(cur ^ 1);         // write tile st+1 (safe: no readers)
        if (st + 2 <= qb) load_tile((st + 2) * 64);  // issue global loads, 2 ahead

        const ushort_t* Kc = Ks[cur];
        const ushort_t* Vc = Vts[cur];
        const bool doA = (st <= qa);
        const bool dgA = (st == qa), dgB = (st == qb);

        // QK^T + softmax-exp, P packed straight into PV A-fragments (regs)
        bf16x8 apA[2], apB[2];
#pragma unroll
        for (int n16 = 0; n16 < 4; n16++) {
            const int rr = (n16 * 16 + ln) * 64;
            bf16x8 bk0 = *(const bf16x8*)&Kc[rr + ((quad ^ rm) << 3)];
            bf16x8 bk1 = *(const bf16x8*)&Kc[rr + (((4 | quad) ^ rm) << 3)];
            const int ks = n16 >> 1, hf = (n16 & 1) * 4;
            __builtin_amdgcn_s_setprio(1);
            f32x4 zB = {0.f, 0.f, 0.f, 0.f};
            zB = __builtin_amdgcn_mfma_f32_16x16x32_bf16(bk0, aqB0, zB, 0, 0, 0);
            zB = __builtin_amdgcn_mfma_f32_16x16x32_bf16(bk1, aqB1, zB, 0, 0, 0);
            f32x4 zA = {0.f, 0.f, 0.f, 0.f};
            if (doA) {
                zA = __builtin_amdgcn_mfma_f32_16x16x32_bf16(bk0, aqA0, zA, 0, 0, 0);
                zA = __builtin_amdgcn_mfma_f32_16x16x32_bf16(bk1, aqA1, zA, 0, 0, 0);
            }
            __builtin_amdgcn_s_setprio(0);
            if (doA) {
#pragma unroll
                for (int r = 0; r < 4; r++) {
                    float v = zA[r];
                    v = (dgA && (n16 * 16 + quad * 4 + r > qrow)) ? -1e30f : v;
                    apA[ks][hf + r] = (bf16_t)__builtin_amdgcn_exp2f(v);
                }
            }
#pragma unroll
            for (int r = 0; r < 4; r++) {
                float v = zB[r];
                v = (dgB && (n16 * 16 + quad * 4 + r > qrow)) ? -1e30f : v;
                apB[ks][hf + r] = (bf16_t)__builtin_amdgcn_exp2f(v);
            }
        }

        // merged PV: each V fragment read once, feeds both phases' MFMAs
        __builtin_amdgcn_s_setprio(1);
#pragma unroll
        for (int ks = 0; ks < 2; ks++) {
            if (doA)
                lA4 = __builtin_amdgcn_mfma_f32_16x16x32_bf16(apA[ks], ones, lA4, 0, 0, 0);
            lB4 = __builtin_amdgcn_mfma_f32_16x16x32_bf16(apB[ks], ones, lB4, 0, 0, 0);
#pragma unroll
            for (int d16 = 0; d16 < 4; d16++) {
                bf16x8 bv = *(const bf16x8*)&Vc[(d16 * 16 + ln) * 64 +
                                                (((ks * 4 + quad) ^ rm) << 3)];
                if (doA)
                    oA[d16] = __builtin_amdgcn_mfma_f32_16x16x32_bf16(apA[ks], bv, oA[d16], 0, 0, 0);
                oB[d16] = __builtin_amdgcn_mfma_f32_16x16x32_bf16(apB[ks], bv, oB[d16], 0, 0, 0);
            }
        }
        __builtin_amdgcn_s_setprio(0);
        __syncthreads();
    }

    // epilogue: normalize (l4 reg r = rowsum of row quad*4+r) and store
#pragma unroll
    for (int ph = 0; ph < 2; ph++) {
        f32x4* o = ph ? oB : oA;
        f32x4 l4 = ph ? lB4 : lA4;
        int qt = ph ? qb : qa;
        f32x4 inv = {1.f / l4[0], 1.f / l4[1], 1.f / l4[2], 1.f / l4[3]};
        const int tg = qt * 64 + wv * 16 + quad * 4;
#pragma unroll
        for (int d16 = 0; d16 < 4; d16++) {
#pragma unroll
            for (int r = 0; r < 4; r++) {
                float v = o[d16][r] * inv[r];
                Y[((size_t)b * T_SEQ + tg + r) * C_DIM + h * HD + d16 * 16 + ln] = f2bf(v);
            }
        }
    }
}

// ---------------------------------------------------------------------------
// Output projection: out[m,n] = sum_k Y[m,k] * Wp[n,k] + bp[n]  (fp32 out)
// SWAP layout -> float4 stores along n.
// ---------------------------------------------------------------------------
__global__ __launch_bounds__(256, 3)
void proj_gemm_kernel(const bf16_t* __restrict__ Yw, const bf16_t* __restrict__ Wpb,
                      const float* __restrict__ bp, float* __restrict__ out) {
    f32x4 acc[4][4];
    gemm_core_128<true>(Yw, Wpb, acc);

    const int tid  = threadIdx.x;
    const int lane = tid & 63;
    const int wv2  = tid >> 6;
    const int wm   = wv2 >> 1, wn = wv2 & 1;
    const int quad = lane >> 4, ln = lane & 15;
    const int mbase = blockIdx.x * 128 + wm * 64;
    const int nbase = blockIdx.y * 128 + wn * 64;

#pragma unroll
    for (int j = 0; j < 4; j++) {
        int nb = nbase + j * 16 + quad * 4;
        float4 b4 = *(const float4*)&bp[nb];
#pragma unroll
        for (int i = 0; i < 4; i++) {
            int m = mbase + i * 16 + ln;
            float4 o4;
            o4.x = acc[i][j][0] + b4.x;
            o4.y = acc[i][j][1] + b4.y;
            o4.z = acc[i][j][2] + b4.z;
            o4.w = acc[i][j][3] + b4.w;
            *(float4*)&out[(size_t)m * C_DIM + nb] = o4;
        }
    }
}

// ---------------------------------------------------------------------------
extern "C" void kernel_launch(void* const* d_in, const int* in_sizes, int n_in,
                              void* d_out, int out_size, void* d_ws, size_t ws_size,
                              hipStream_t stream) {
    const float* x  = (const float*)d_in[0];
    const float* Wq = (const float*)d_in[1];
    const float* bq = (const float*)d_in[2];
    const float* Wk = (const float*)d_in[3];
    const float* bk = (const float*)d_in[4];
    const float* Wv = (const float*)d_in[5];
    const float* bv = (const float*)d_in[6];
    const float* Wp = (const float*)d_in[7];
    const float* bp = (const float*)d_in[8];
    float* out = (float*)d_out;

    char* ws = (char*)d_ws;
    const size_t MB = (size_t)1 << 20;
    ushort_t* Qw = (ushort_t*)(ws);            // 16 MB  [B,H,T,D] bf16 (pre-scaled)
    ushort_t* Kw = (ushort_t*)(ws + 16 * MB);  // 16 MB  [B,H,T,D] bf16
    ushort_t* Vt = (ushort_t*)(ws + 32 * MB);  // 16 MB  [B,H,D,T] bf16
    ushort_t* Yw = (ushort_t*)(ws + 48 * MB);  // 16 MB  [B,T,C]   bf16

    // Wp-bf16 placement: past the 64MB working set if ws allows (converted
    // up-front in cvt_all), else the dead Qw region (converted after flash).
    const bool big_ws = ws_size >= 66 * MB;
    ushort_t* Wpb = big_ws ? (ushort_t*)(ws + 64 * MB) : (ushort_t*)(ws);

    // d_out doubles as bf16 scratch for converted inputs; proj overwrites it.
    ushort_t* xb  = (ushort_t*)out;                     // 16 MB
    ushort_t* Wqb = (ushort_t*)((char*)out + 16 * MB);  // 2 MB
    ushort_t* Wkb = (ushort_t*)((char*)out + 18 * MB);  // 2 MB
    ushort_t* Wvb = (ushort_t*)((char*)out + 20 * MB);  // 2 MB

    cvt_all_kernel<<<big_ws ? 12288 : 11264, 256, 0, stream>>>(
        x, Wq, Wk, Wv, Wp, xb, Wqb, Wkb, Wvb, Wpb);

    dim3 g1(64, 8, 2);
    qk_gemm_kernel<<<g1, 256, 0, stream>>>((const bf16_t*)xb,
                                           (const bf16_t*)Wqb, bq,
                                           (const bf16_t*)Wkb, bk,
                                           Qw, Kw);

    dim3 g1v(64, 8, 1);
    v_gemm_kernel<<<g1v, 256, 0, stream>>>((const bf16_t*)xb,
                                           (const bf16_t*)Wvb, bv, Vt);

    dim3 g2(16, 64);   // (paired q-tiles, B*H)
    flash_kernel<<<g2, 256, 0, stream>>>(Qw, Kw, Vt, Yw);

    if (!big_ws)
        cvt_wp_kernel<<<1024, 256, 0, stream>>>(Wp, Wpb);

    dim3 g3(64, 8, 1);
    proj_gemm_kernel<<<g3, 256, 0, stream>>>((const bf16_t*)Yw, (const bf16_t*)Wpb, bp, out);
}

// Round 7
// 234.285 us; speedup vs baseline: 1.1074x; 1.1074x over previous
//
#include <hip/hip_runtime.h>

typedef __bf16 bf16_t;
typedef __bf16 bf16x8 __attribute__((ext_vector_type(8)));
typedef __bf16 bf16x4 __attribute__((ext_vector_type(4)));
typedef float f32x4 __attribute__((ext_vector_type(4)));
typedef unsigned short ushort_t;

#define T_SEQ 2048
#define C_DIM 1024
#define NH    16
#define HD    64

__device__ __forceinline__ ushort_t f2bf(float f) {
    unsigned u = __builtin_bit_cast(unsigned, f);
    u += 0x7FFFu + ((u >> 16) & 1u);   // RNE
    return (ushort_t)(u >> 16);
}

// async 16B global -> LDS (direct, no VGPR round-trip)
__device__ __forceinline__ void async_cp16(const void* g, void* l) {
    __builtin_amdgcn_global_load_lds(
        (const __attribute__((address_space(1))) void*)g,
        (__attribute__((address_space(3))) void*)l, 16, 0, 0);
}

// ---------------------------------------------------------------------------
// Unified fp32 -> bf16 conversion for x, Wq, Wk, Wv (+ optionally Wp).
// ---------------------------------------------------------------------------
#define X4  2097152
#define W4  262144
__global__ __launch_bounds__(256)
void cvt_all_kernel(const float* __restrict__ x,  const float* __restrict__ Wq,
                    const float* __restrict__ Wk, const float* __restrict__ Wv,
                    const float* __restrict__ Wp,
                    ushort_t* __restrict__ xb,  ushort_t* __restrict__ Wqb,
                    ushort_t* __restrict__ Wkb, ushort_t* __restrict__ Wvb,
                    ushort_t* __restrict__ Wpb) {
    int i = blockIdx.x * 256 + threadIdx.x;
    const float* src; ushort_t* dst; int off;
    if (i < X4)                { src = x;  dst = xb;  off = i; }
    else if (i < X4 + W4)      { src = Wq; dst = Wqb; off = i - X4; }
    else if (i < X4 + 2 * W4)  { src = Wk; dst = Wkb; off = i - X4 - W4; }
    else if (i < X4 + 3 * W4)  { src = Wv; dst = Wvb; off = i - X4 - 2 * W4; }
    else                       { src = Wp; dst = Wpb; off = i - X4 - 3 * W4; }
    float4 f = ((const float4*)src)[off];
    ushort4 u;
    u.x = f2bf(f.x); u.y = f2bf(f.y); u.z = f2bf(f.z); u.w = f2bf(f.w);
    ((ushort4*)dst)[off] = u;
}

// fp32 -> bf16 for Wp (fallback: runs after flash into the dead Qw region)
__global__ __launch_bounds__(256)
void cvt_wp_kernel(const float* __restrict__ Wp, ushort_t* __restrict__ Wpb) {
    int i = blockIdx.x * 256 + threadIdx.x;   // 262144 float4
    float4 f = ((const float4*)Wp)[i];
    ushort4 u;
    u.x = f2bf(f.x); u.y = f2bf(f.y); u.z = f2bf(f.z); u.w = f2bf(f.w);
    ((ushort4*)Wpb)[i] = u;
}

// ---------------------------------------------------------------------------
// GEMM core: 128x128 tile, BK=64, 256 threads (4 waves, 2x2), NT layout,
// all-bf16.  Staging via global_load_lds (16B/lane, linear LDS dest).
// XOR swizzle via pre-swizzled GLOBAL source; fragment reads apply the same
// involution -> conflict-free ds_read_b128.
// SWAP=false: acc[i][j] holds C[m = i*16+quad*4+r][n = j*16+ln]
// SWAP=true : mfma(bfr, af) -> acc[i][j] holds C[m = i*16+ln][n = j*16+quad*4+r]
// NOTE: each __global__ kernel must instantiate EXACTLY ONE variant —
// instantiating both in one kernel doubles static LDS (R4 regression).
// ---------------------------------------------------------------------------
template<bool SWAP>
__device__ __forceinline__ void gemm_core_128(const bf16_t* __restrict__ A,
                                              const bf16_t* __restrict__ B,
                                              f32x4 (&acc)[4][4]) {
    __shared__ alignas(16) ushort_t As[128 * 64];
    __shared__ alignas(16) ushort_t Ws[128 * 64];
    const int tid  = threadIdx.x;
    const int lane = tid & 63;
    const int wv   = tid >> 6;
    const int wm   = wv >> 1, wn = wv & 1;
    const int quad = lane >> 4, ln = lane & 15;
    const int m0 = blockIdx.x * 128, n0 = blockIdx.y * 128;

    f32x4 z4 = {0.f, 0.f, 0.f, 0.f};
#pragma unroll
    for (int i = 0; i < 4; i++)
#pragma unroll
        for (int j = 0; j < 4; j++) acc[i][j] = z4;

    const int lr = lane >> 3;            // row within 8-row chunk
    const int lc = (lane & 7) ^ lr;      // swizzled source 16B-block
    const bf16_t* Ab = A + (size_t)(m0 + wv * 32 + lr) * 1024 + lc * 8;
    const bf16_t* Bb = B + (size_t)(n0 + wv * 32 + lr) * 1024 + lc * 8;

    for (int kt = 0; kt < 1024; kt += 64) {
#pragma unroll
        for (int p = 0; p < 4; ++p) {
            async_cp16(Ab + (size_t)p * 8192 + kt, &As[(wv * 4 + p) * 512]);
            async_cp16(Bb + (size_t)p * 8192 + kt, &Ws[(wv * 4 + p) * 512]);
        }
        __syncthreads();
#pragma unroll
        for (int ks = 0; ks < 2; ++ks) {
            bf16x8 af[4], bfr[4];
#pragma unroll
            for (int i = 0; i < 4; i++)
                af[i] = *(const bf16x8*)&As[(wm * 64 + i * 16 + ln) * 64 +
                                            (((ks * 4 + quad) ^ (ln & 7)) * 8)];
#pragma unroll
            for (int j = 0; j < 4; j++)
                bfr[j] = *(const bf16x8*)&Ws[(wn * 64 + j * 16 + ln) * 64 +
                                             (((ks * 4 + quad) ^ (ln & 7)) * 8)];
#pragma unroll
            for (int i = 0; i < 4; i++)
#pragma unroll
                for (int j = 0; j < 4; j++)
                    acc[i][j] = SWAP
                        ? __builtin_amdgcn_mfma_f32_16x16x32_bf16(bfr[j], af[i],
                                                                  acc[i][j], 0, 0, 0)
                        : __builtin_amdgcn_mfma_f32_16x16x32_bf16(af[i], bfr[j],
                                                                  acc[i][j], 0, 0, 0);
        }
        __syncthreads();
    }
}

// ---------------------------------------------------------------------------
// Unified QKV projection (all-bf16 inputs), ONE dispatch (grid z=3), one
// gemm_core instantiation.  z=0: Q (pre-scaled) -> [B,H,T,D]; z=1: K ->
// [B,H,T,D]; z=2: V -> [B,H,D,T].  (R7: restored from R3 — the qk/v split
// cost ~8 us vs this unified form.)
// ---------------------------------------------------------------------------
__global__ __launch_bounds__(256, 3)
void qkv_gemm_kernel(const bf16_t* __restrict__ xb,
                     const bf16_t* __restrict__ Wqb, const float* __restrict__ bq,
                     const bf16_t* __restrict__ Wkb, const float* __restrict__ bk,
                     const bf16_t* __restrict__ Wvb, const float* __restrict__ bv,
                     ushort_t* __restrict__ Qo, ushort_t* __restrict__ Ko,
                     ushort_t* __restrict__ Vo) {
    const int z = blockIdx.z;
    const bf16_t* W   = (z == 0) ? Wqb : (z == 1) ? Wkb : Wvb;
    const float* bias = (z == 0) ? bq : (z == 1) ? bk : bv;
    ushort_t* outp    = (z == 0) ? Qo : (z == 1) ? Ko : Vo;
    const float fs    = (z == 0) ? 0.18033688011112042f : 1.0f;  // (1/8)*log2(e)

    f32x4 acc[4][4];
    gemm_core_128<false>(xb, W, acc);

    const int tid  = threadIdx.x;
    const int lane = tid & 63;
    const int wv2  = tid >> 6;
    const int wm   = wv2 >> 1, wn = wv2 & 1;
    const int quad = lane >> 4, ln = lane & 15;
    const int mbase = blockIdx.x * 128 + wm * 64;
    const int nbase = blockIdx.y * 128 + wn * 64;

#pragma unroll
    for (int j = 0; j < 4; j++) {
        int n = nbase + j * 16 + ln;
        float bj = bias[n];
        int h = n >> 6, d = n & 63;
#pragma unroll
        for (int i = 0; i < 4; i++) {
            int mr = mbase + i * 16 + quad * 4;
            int b = mr >> 11;
            int t = mr & 2047;
            if (z < 2) {
                ushort_t* op = outp + ((size_t)(b * NH + h) * T_SEQ + t) * HD + d;
#pragma unroll
                for (int r = 0; r < 4; r++)
                    op[(size_t)r * HD] = f2bf((acc[i][j][r] + bj) * fs);
            } else {
                ushort4 us;
                us.x = f2bf(acc[i][j][0] + bj);
                us.y = f2bf(acc[i][j][1] + bj);
                us.z = f2bf(acc[i][j][2] + bj);
                us.w = f2bf(acc[i][j][3] + bj);
                *(ushort4*)(outp + ((size_t)(b * NH + h) * HD + d) * T_SEQ + t) = us;
            }
        }
    }
}

// ---------------------------------------------------------------------------
// Flash attention (causal), paired q-tiles (p, 31-p), P HELD IN REGISTERS,
// K/V LDS DOUBLE-BUFFERED (stride-72), ONE barrier per iteration, 2-tile-deep
// global prefetch.  R7: causal-mask iterations PEELED — interior iterations
// carry zero mask VALU (macro instantiated with literal flags).
//
// Swapped QK: zz = mfma(K,Q) -> lane (quad,ln) holds P[q=ln][s=n16*16+quad*4+r].
// PV uses a PERMUTED k-order matching where those values already sit; V is
// staged into LDS in the same s-permutation (vkpos).  Rowsum-MFMA vs ones is
// permutation-invariant.
// ---------------------------------------------------------------------------
__device__ __forceinline__ int vkpos(int s) {   // k-slot position of s in [0,64)
    return 32 * (s >> 5) + 8 * ((s >> 2) & 3) + 4 * ((s >> 4) & 1) + (s & 3);
}

#define FLASH_ITER(ST, DOA, DGA, DGB)                                          \
  {                                                                            \
    const int cur_ = (ST) & 1;                                                 \
    if ((ST) < qb) store_tile(cur_ ^ 1);                                       \
    if ((ST) + 2 <= qb) load_tile(((ST) + 2) * 64);                            \
    const ushort_t* Kc = Ks[cur_];                                             \
    const ushort_t* Vc = Vts[cur_];                                            \
    bf16x8 apA[2], apB[2];                                                     \
    _Pragma("unroll")                                                          \
    for (int n16 = 0; n16 < 4; n16++) {                                        \
      bf16x8 bk0 = *(const bf16x8*)&Kc[(n16 * 16 + ln) * 72 + quad * 8];       \
      bf16x8 bk1 = *(const bf16x8*)&Kc[(n16 * 16 + ln) * 72 + 32 + quad * 8];  \
      const int ks_ = n16 >> 1, hf_ = (n16 & 1) * 4;                           \
      f32x4 zB = {0.f, 0.f, 0.f, 0.f};                                         \
      zB = __builtin_amdgcn_mfma_f32_16x16x32_bf16(bk0, aqB0, zB, 0, 0, 0);    \
      zB = __builtin_amdgcn_mfma_f32_16x16x32_bf16(bk1, aqB1, zB, 0, 0, 0);    \
      if (DOA) {                                                               \
        f32x4 zA = {0.f, 0.f, 0.f, 0.f};                                       \
        zA = __builtin_amdgcn_mfma_f32_16x16x32_bf16(bk0, aqA0, zA, 0, 0, 0);  \
        zA = __builtin_amdgcn_mfma_f32_16x16x32_bf16(bk1, aqA1, zA, 0, 0, 0);  \
        _Pragma("unroll")                                                      \
        for (int r = 0; r < 4; r++) {                                          \
          float v = zA[r];                                                     \
          if (DGA) v = (n16 * 16 + quad * 4 + r > qrow) ? -1e30f : v;          \
          apA[ks_][hf_ + r] = (bf16_t)__builtin_amdgcn_exp2f(v);               \
        }                                                                      \
      }                                                                        \
      _Pragma("unroll")                                                        \
      for (int r = 0; r < 4; r++) {                                            \
        float v = zB[r];                                                       \
        if (DGB) v = (n16 * 16 + quad * 4 + r > qrow) ? -1e30f : v;            \
        apB[ks_][hf_ + r] = (bf16_t)__builtin_amdgcn_exp2f(v);                 \
      }                                                                        \
    }                                                                          \
    _Pragma("unroll")                                                          \
    for (int ks2 = 0; ks2 < 2; ks2++) {                                        \
      if (DOA)                                                                 \
        lA4 = __builtin_amdgcn_mfma_f32_16x16x32_bf16(apA[ks2], ones, lA4, 0, 0, 0); \
      lB4 = __builtin_amdgcn_mfma_f32_16x16x32_bf16(apB[ks2], ones, lB4, 0, 0, 0);   \
      _Pragma("unroll")                                                        \
      for (int d16 = 0; d16 < 4; d16++) {                                      \
        bf16x8 bv = *(const bf16x8*)&Vc[(d16 * 16 + ln) * 72 + ks2 * 32 + quad * 8]; \
        if (DOA)                                                               \
          oA[d16] = __builtin_amdgcn_mfma_f32_16x16x32_bf16(apA[ks2], bv, oA[d16], 0, 0, 0); \
        oB[d16] = __builtin_amdgcn_mfma_f32_16x16x32_bf16(apB[ks2], bv, oB[d16], 0, 0, 0);   \
      }                                                                        \
    }                                                                          \
    __syncthreads();                                                           \
  }

__global__ __launch_bounds__(256, 4)
void flash_kernel(const ushort_t* __restrict__ Qw, const ushort_t* __restrict__ Kw,
                  const ushort_t* __restrict__ Vt, ushort_t* __restrict__ Y) {
    __shared__ alignas(16) ushort_t Ks[2][64 * 72];
    __shared__ alignas(16) ushort_t Vts[2][64 * 72];

    const int tid  = threadIdx.x;
    const int lane = tid & 63;
    const int wv   = tid >> 6;
    const int quad = lane >> 4, ln = lane & 15;
    // bijective XCD-aware remap of (p, bh)
    const int L  = blockIdx.y * 16 + blockIdx.x;      // hw dispatch-linear id
    const int m  = L >> 3;
    const int bh = ((m >> 4) << 3) | (L & 7);         // same bh -> same L%8 (XCD)
    const int p  = m & 15;                            // 0..15
    const int qa = p, qb = 31 - p;                    // qa <= 15 < 16 <= qb
    const int b = bh >> 4, h = bh & 15;

    bf16x8 ones;
#pragma unroll
    for (int i = 0; i < 8; i++) ones[i] = (bf16_t)1.0f;

    const ushort_t* qpa = Qw + ((size_t)bh * T_SEQ + qa * 64 + wv * 16 + ln) * HD;
    const ushort_t* qpb = Qw + ((size_t)bh * T_SEQ + qb * 64 + wv * 16 + ln) * HD;
    bf16x8 aqA0 = *(const bf16x8*)(qpa + quad * 8);
    bf16x8 aqA1 = *(const bf16x8*)(qpa + 32 + quad * 8);
    bf16x8 aqB0 = *(const bf16x8*)(qpb + quad * 8);
    bf16x8 aqB1 = *(const bf16x8*)(qpb + 32 + quad * 8);

    f32x4 oA[4], oB[4];
    f32x4 z4 = {0.f, 0.f, 0.f, 0.f};
#pragma unroll
    for (int i = 0; i < 4; i++) { oA[i] = z4; oB[i] = z4; }
    f32x4 lA4 = z4, lB4 = z4;

    const int row0 = tid >> 3, c80 = (tid & 7) * 8;
    const int row1 = row0 + 32;
    const int kp0 = vkpos(c80);          // V k-slot for s = c80..c80+3
    const int kp1 = vkpos(c80 + 4);      // V k-slot for s = c80+4..c80+7

    uint4 pk0, pk1, pv0, pv1;
    auto load_tile = [&](int sb) {
        pk0 = *(const uint4*)(Kw + ((size_t)bh * T_SEQ + sb + row0) * HD + c80);
        pv0 = *(const uint4*)(Vt + ((size_t)bh * HD + row0) * T_SEQ + sb + c80);
        pk1 = *(const uint4*)(Kw + ((size_t)bh * T_SEQ + sb + row1) * HD + c80);
        pv1 = *(const uint4*)(Vt + ((size_t)bh * HD + row1) * T_SEQ + sb + c80);
    };
    auto store_tile = [&](int bs) {
        *(uint4*)&Ks[bs][row0 * 72 + c80] = pk0;
        *(uint4*)&Ks[bs][row1 * 72 + c80] = pk1;
        uint2 a0 = {pv0.x, pv0.y}, a1 = {pv0.z, pv0.w};
        uint2 b0 = {pv1.x, pv1.y}, b1 = {pv1.z, pv1.w};
        *(uint2*)&Vts[bs][row0 * 72 + kp0] = a0;
        *(uint2*)&Vts[bs][row0 * 72 + kp1] = a1;
        *(uint2*)&Vts[bs][row1 * 72 + kp0] = b0;
        *(uint2*)&Vts[bs][row1 * 72 + kp1] = b1;
    };

    const int qrow = wv * 16 + ln;       // this lane's q position within tile

    // prologue: tile0 -> buf0; regs hold tile1; invariant at loop entry:
    //   buf[st&1] is full with tile st, regs hold tile st+1
    load_tile(0);
    store_tile(0);
    load_tile(64);
    __syncthreads();

    // peeled schedule: interior iterations carry no mask VALU
    {
        int st = 0;
        for (; st < qa; ++st) FLASH_ITER(st, true, false, false);
        FLASH_ITER(qa, true, true, false);
        for (st = qa + 1; st < qb; ++st) FLASH_ITER(st, false, false, false);
        FLASH_ITER(qb, false, false, true);
    }

    // epilogue: normalize (l4 reg r = rowsum of row quad*4+r) and store
#pragma unroll
    for (int ph = 0; ph < 2; ph++) {
        f32x4* o = ph ? oB : oA;
        f32x4 l4 = ph ? lB4 : lA4;
        int qt = ph ? qb : qa;
        f32x4 inv = {1.f / l4[0], 1.f / l4[1], 1.f / l4[2], 1.f / l4[3]};
        const int tg = qt * 64 + wv * 16 + quad * 4;
#pragma unroll
        for (int d16 = 0; d16 < 4; d16++) {
#pragma unroll
            for (int r = 0; r < 4; r++) {
                float v = o[d16][r] * inv[r];
                Y[((size_t)b * T_SEQ + tg + r) * C_DIM + h * HD + d16 * 16 + ln] = f2bf(v);
            }
        }
    }
}

// ---------------------------------------------------------------------------
// Output projection: out[m,n] = sum_k Y[m,k] * Wp[n,k] + bp[n]  (fp32 out)
// SWAP layout -> float4 stores along n.
// ---------------------------------------------------------------------------
__global__ __launch_bounds__(256, 3)
void proj_gemm_kernel(const bf16_t* __restrict__ Yw, const bf16_t* __restrict__ Wpb,
                      const float* __restrict__ bp, float* __restrict__ out) {
    f32x4 acc[4][4];
    gemm_core_128<true>(Yw, Wpb, acc);

    const int tid  = threadIdx.x;
    const int lane = tid & 63;
    const int wv2  = tid >> 6;
    const int wm   = wv2 >> 1, wn = wv2 & 1;
    const int quad = lane >> 4, ln = lane & 15;
    const int mbase = blockIdx.x * 128 + wm * 64;
    const int nbase = blockIdx.y * 128 + wn * 64;

#pragma unroll
    for (int j = 0; j < 4; j++) {
        int nb = nbase + j * 16 + quad * 4;
        float4 b4 = *(const float4*)&bp[nb];
#pragma unroll
        for (int i = 0; i < 4; i++) {
            int m = mbase + i * 16 + ln;
            float4 o4;
            o4.x = acc[i][j][0] + b4.x;
            o4.y = acc[i][j][1] + b4.y;
            o4.z = acc[i][j][2] + b4.z;
            o4.w = acc[i][j][3] + b4.w;
            *(float4*)&out[(size_t)m * C_DIM + nb] = o4;
        }
    }
}

// ---------------------------------------------------------------------------
extern "C" void kernel_launch(void* const* d_in, const int* in_sizes, int n_in,
                              void* d_out, int out_size, void* d_ws, size_t ws_size,
                              hipStream_t stream) {
    const float* x  = (const float*)d_in[0];
    const float* Wq = (const float*)d_in[1];
    const float* bq = (const float*)d_in[2];
    const float* Wk = (const float*)d_in[3];
    const float* bk = (const float*)d_in[4];
    const float* Wv = (const float*)d_in[5];
    const float* bv = (const float*)d_in[6];
    const float* Wp = (const float*)d_in[7];
    const float* bp = (const float*)d_in[8];
    float* out = (float*)d_out;

    char* ws = (char*)d_ws;
    const size_t MB = (size_t)1 << 20;
    ushort_t* Qw = (ushort_t*)(ws);            // 16 MB  [B,H,T,D] bf16 (pre-scaled)
    ushort_t* Kw = (ushort_t*)(ws + 16 * MB);  // 16 MB  [B,H,T,D] bf16
    ushort_t* Vt = (ushort_t*)(ws + 32 * MB);  // 16 MB  [B,H,D,T] bf16
    ushort_t* Yw = (ushort_t*)(ws + 48 * MB);  // 16 MB  [B,T,C]   bf16

    // Wp-bf16 placement: past the 64MB working set if ws allows (converted
    // up-front in cvt_all), else the dead Qw region (converted after flash).
    const bool big_ws = ws_size >= 66 * MB;
    ushort_t* Wpb = big_ws ? (ushort_t*)(ws + 64 * MB) : (ushort_t*)(ws);

    // d_out doubles as bf16 scratch for converted inputs; proj overwrites it.
    ushort_t* xb  = (ushort_t*)out;                     // 16 MB
    ushort_t* Wqb = (ushort_t*)((char*)out + 16 * MB);  // 2 MB
    ushort_t* Wkb = (ushort_t*)((char*)out + 18 * MB);  // 2 MB
    ushort_t* Wvb = (ushort_t*)((char*)out + 20 * MB);  // 2 MB

    cvt_all_kernel<<<big_ws ? 12288 : 11264, 256, 0, stream>>>(
        x, Wq, Wk, Wv, Wp, xb, Wqb, Wkb, Wvb, Wpb);

    dim3 g1(64, 8, 3);
    qkv_gemm_kernel<<<g1, 256, 0, stream>>>((const bf16_t*)xb,
                                            (const bf16_t*)Wqb, bq,
                                            (const bf16_t*)Wkb, bk,
                                            (const bf16_t*)Wvb, bv,
                                            Qw, Kw, Vt);

    dim3 g2(16, 64);   // (paired q-tiles, B*H)
    flash_kernel<<<g2, 256, 0, stream>>>(Qw, Kw, Vt, Yw);

    if (!big_ws)
        cvt_wp_kernel<<<1024, 256, 0, stream>>>(Wp, Wpb);

    dim3 g3(64, 8, 1);
    proj_gemm_kernel<<<g3, 256, 0, stream>>>((const bf16_t*)Yw, (const bf16_t*)Wpb, bp, out);
}